// Round 3
// baseline (8756.438 us; speedup 1.0000x reference)
//
#include <hip/hip_runtime.h>
#include <hip/hip_bf16.h>

#define N_NODES 100000
#define N_EDGES 1600000
#define DIM 128
#define NLAY 3
#define NRES 3
#define NCODE 16
#define NGRAPH 512

using bf16 = __hip_bfloat16;

__device__ inline void atomAddD(double* p, double v) { unsafeAtomicAdd(p, v); }

// flag==1: external float-typed arrays are bf16; flag==0: they are fp32.
__device__ inline double ldx(const void* p, long i, int isbf) {
  if (isbf) return (double)__bfloat162float(((const bf16*)p)[i]);
  return (double)((const float*)p)[i];
}
__device__ inline void stout(void* p, long i, double v, int isbf) {
  if (isbf) ((bf16*)p)[i] = __float2bfloat16((float)v);
  else ((float*)p)[i] = (float)v;
}

// ---------- dtype detection: bf16 vs fp32 bit-pattern statistics ----------
__global__ void k_detect(const unsigned int* __restrict__ x, int* __restrict__ flag) {
  int tid = threadIdx.x;  // 256
  int cnt = 0;
  for (int j = tid; j < 1024; j += 256) {
    unsigned int u = x[j];
    int e = (u >> 7) & 0xFF;  // exponent field of the LOW u16 viewed as bf16
    cnt += (e >= 100 && e <= 135) ? 1 : 0;
  }
  __shared__ int sh[256];
  sh[tid] = cnt; __syncthreads();
  for (int s = 128; s; s >>= 1) { if (tid < s) sh[tid] += sh[tid + s]; __syncthreads(); }
  if (tid == 0) flag[0] = (sh[0] > 512) ? 1 : 0;
}

// ---------- external -> fp64 convert ----------
__global__ __launch_bounds__(256) void k_convert(const void* __restrict__ x, double* __restrict__ A,
                                                 long n, const int* __restrict__ flag) {
  int isbf = flag[0];
  long i = (long)blockIdx.x * 256 + threadIdx.x;
  if (i < n) A[i] = ldx(x, i, isbf);
}

// ---------- copy (double2) ----------
__global__ __launch_bounds__(256) void k_copy(const double* __restrict__ src, double* __restrict__ dst) {
  long i = (long)blockIdx.x * 256 + threadIdx.x;
  double2 v = ((const double2*)src)[i];
  ((double2*)dst)[i] = v;
}

// ---------- normalize codebooks (fp64) ----------
__global__ void k_cbn(const void* __restrict__ cb, double* __restrict__ cbn, const int* __restrict__ flag) {
  int isbf = flag[0];
  int b = blockIdx.x, d = threadIdx.x;  // 144 blocks x 64 threads
  double v0 = ldx(cb, (long)b * DIM + d, isbf);
  double v1 = ldx(cb, (long)b * DIM + d + 64, isbf);
  double ss = v0 * v0 + v1 * v1;
  for (int o = 32; o; o >>= 1) ss += __shfl_xor(ss, o);
  double inv = 1.0 / sqrt(ss + 1e-12);
  cbn[b * DIM + d] = v0 * inv;
  cbn[b * DIM + d + 64] = v1 * inv;
}

// ---------- Gram matrices per layer ----------
__global__ void k_gram(const double* __restrict__ cbn, double* __restrict__ G) {
  int b = blockIdx.x, t = threadIdx.x;  // 3*48*48 blocks x 64
  int l = b / (48 * 48); int rem = b % (48 * 48); int a = rem / 48, c = rem % 48;
  const double* ra = cbn + (long)(l * 48 + a) * DIM;
  const double* rc = cbn + (long)(l * 48 + c) * DIM;
  double s = ra[t] * rc[t] + ra[t + 64] * rc[t + 64];
  for (int o = 32; o; o >>= 1) s += __shfl_xor(s, o);
  if (t == 0) G[b] = s;
}

// ---------- edge scatter: agg[dst] += h[src] (agg pre-initialized to h) ----------
__global__ __launch_bounds__(256) void k_scatter(const int* __restrict__ ei,
                                                 const double* __restrict__ h,
                                                 double* __restrict__ agg) {
  long gid = (long)blockIdx.x * 256 + threadIdx.x;
  int e = (int)(gid >> 6); int lane = (int)(gid & 63);
  int s = ei[e], d = ei[N_EDGES + e];
  double2 v = *(const double2*)&h[(long)s * DIM + lane * 2];
  double* o = &agg[(long)d * DIM + lane * 2];
  atomAddD(o, v.x);
  atomAddD(o + 1, v.y);
}

// ---------- fp64 GEMM + bias + relu ----------
__global__ __launch_bounds__(256) void k_gemm_relu(const double* __restrict__ in,
                                                   const double* __restrict__ W,
                                                   const double* __restrict__ bias,
                                                   double* __restrict__ out) {
  __shared__ double ul[32 * DIM];
  int tid = threadIdx.x;
  long base = (long)blockIdx.x * 32;
  for (int j = tid; j < 32 * DIM; j += 256) ul[j] = in[base * DIM + j];
  __syncthreads();
  int c = 2 * (tid & 63);
  int tr = tid >> 6;
  double acc[8][2] = {};
  for (int k = 0; k < DIM; k += 2) {
    double2 wa = *(const double2*)&W[k * DIM + c];
    double2 wb = *(const double2*)&W[(k + 1) * DIM + c];
#pragma unroll
    for (int rg = 0; rg < 8; rg++) {
      double2 u = *(const double2*)&ul[(rg * 4 + tr) * DIM + k];
      acc[rg][0] += u.x * wa.x + u.y * wb.x;
      acc[rg][1] += u.x * wa.y + u.y * wb.y;
    }
  }
  double2 bv = *(const double2*)&bias[c];
#pragma unroll
  for (int rg = 0; rg < 8; rg++) {
    double v0 = acc[rg][0] + bv.x;
    double v1 = acc[rg][1] + bv.y;
    v0 = v0 > 0.0 ? v0 : 0.0;
    v1 = v1 > 0.0 ? v1 : 0.0;
    *(double2*)&out[(base + rg * 4 + tr) * DIM + c] = make_double2(v0, v1);
  }
}

// ---------- BN stats ----------
__global__ __launch_bounds__(256) void k_bn_stats(const double* __restrict__ h, double* __restrict__ stats) {
  int tid = threadIdx.x; int col = tid & 127; int half = tid >> 7;
  double s = 0.0, s2 = 0.0;
  for (long r = blockIdx.x * 2 + half; r < N_NODES; r += 2048) {
    double v = h[r * DIM + col];
    s += v; s2 += v * v;
  }
  __shared__ double ls[256], ls2[256];
  ls[tid] = s; ls2[tid] = s2;
  __syncthreads();
  if (tid < 128) {
    atomAddD(&stats[col], ls[tid] + ls[tid + 128]);
    atomAddD(&stats[DIM + col], ls2[tid] + ls2[tid + 128]);
  }
}

// ---------- BN prep ----------
__global__ void k_bn_prep(const double* __restrict__ stats, const void* __restrict__ gamma,
                          const void* __restrict__ beta, double* __restrict__ ss,
                          int l, const int* __restrict__ flag) {
  int isbf = flag[0];
  int d = threadIdx.x;  // 128
  double mean = stats[d] / (double)N_NODES;
  double var = stats[DIM + d] / (double)N_NODES - mean * mean;
  double sc = ldx(gamma, (long)l * DIM + d, isbf) / sqrt(var + 1e-5);
  ss[d] = sc;
  ss[DIM + d] = ldx(beta, (long)l * DIM + d, isbf) - mean * sc;
}

// ---------- normalize in place + xs out + xpool + ||h||^2 ----------
// xs element index (within d_out): XS_BASE + n*384 + l*128 + d
__global__ __launch_bounds__(256) void k_normalize(double* __restrict__ h, const double* __restrict__ ss,
                                                   const int* __restrict__ batch, void* __restrict__ out,
                                                   double* __restrict__ xpool, double* __restrict__ hh,
                                                   int l, const int* __restrict__ flag) {
  int isbf = flag[0];
  int tid = threadIdx.x;
  int n = blockIdx.x * 2 + (tid >> 7);
  int d = tid & 127;
  double v = h[(long)n * DIM + d] * ss[d] + ss[DIM + d];
  h[(long)n * DIM + d] = v;
  const long XS_BASE = (long)NGRAPH * DIM * NLAY;
  stout(out, XS_BASE + (long)n * (DIM * NLAY) + l * DIM + d, v, isbf);
  int g = batch[n];
  atomAddD(&xpool[(long)g * (DIM * NLAY) + l * DIM + d], v);
  double s2 = v * v;
  for (int o = 32; o; o >>= 1) s2 += __shfl_xor(s2, o);
  __shared__ double wp[4];
  if ((tid & 63) == 0) wp[tid >> 6] = s2;
  __syncthreads();
  if (tid == 0) hh[n] = wp[0] + wp[1];
  else if (tid == 128) hh[n] = wp[2] + wp[3];
}

// ---------- dotH = h_norm @ cbn^T (48 cols), fp64 ----------
__global__ __launch_bounds__(256) void k_dotH(const double* __restrict__ hn,
                                              const double* __restrict__ cbnL,
                                              double* __restrict__ dH) {
  __shared__ double cl[48 * 134];
  int tid = threadIdx.x;
  for (int j = tid; j < 48 * DIM; j += 256) { int c = j >> 7, k = j & 127; cl[c * 134 + k] = cbnL[j]; }
  __syncthreads();
  int ct = tid & 7; int c0 = ct * 6; int rt = tid >> 3;
  long r0 = (long)blockIdx.x * 64 + rt; long r1 = r0 + 32;
  long r0c = r0 < N_NODES ? r0 : (N_NODES - 1);
  long r1c = r1 < N_NODES ? r1 : (N_NODES - 1);
  double acc0[6] = {}, acc1[6] = {};
  for (int k = 0; k < DIM; k += 2) {
    double2 h0 = *(const double2*)&hn[r0c * DIM + k];
    double2 h1 = *(const double2*)&hn[r1c * DIM + k];
#pragma unroll
    for (int j = 0; j < 6; j++) {
      double2 cv = *(const double2*)&cl[(c0 + j) * 134 + k];
      acc0[j] += h0.x * cv.x + h0.y * cv.y;
      acc1[j] += h1.x * cv.x + h1.y * cv.y;
    }
  }
  if (r0 < N_NODES) {
#pragma unroll
    for (int j = 0; j < 6; j++) dH[r0 * 48 + c0 + j] = acc0[j];
  }
  if (r1 < N_NODES) {
#pragma unroll
    for (int j = 0; j < 6; j++) dH[r1 * 48 + c0 + j] = acc1[j];
  }
}

// ---------- VQ select via dotH & Gram; ids + commit ----------
// ids element index: IDS_BASE + n*9 + l*3 + r
__global__ __launch_bounds__(256) void k_vq(const double* __restrict__ dH, const double* __restrict__ hh,
                                            const double* __restrict__ G, void* __restrict__ out,
                                            double* __restrict__ commit, int l, const int* __restrict__ flag) {
  int isbf = flag[0];
  __shared__ double Gl[48 * 48];
  int tid = threadIdx.x;
  for (int j = tid; j < 48 * 48; j += 256) Gl[j] = G[j];
  __syncthreads();
  long n = (long)blockIdx.x * 256 + tid;
  double csum = 0.0;
  if (n < N_NODES) {
    double dh[48];
#pragma unroll
    for (int c = 0; c < 48; c++) dh[c] = dH[n * 48 + c];
    int i0 = 0; double b0 = dh[0];
#pragma unroll
    for (int c = 1; c < 16; c++) { if (dh[c] > b0) { b0 = dh[c]; i0 = c; } }
    int i1 = 0; double b1 = dh[16] - Gl[i0 * 48 + 16];
#pragma unroll
    for (int c = 1; c < 16; c++) {
      double s = dh[16 + c] - Gl[i0 * 48 + 16 + c];
      if (s > b1) { b1 = s; i1 = c; }
    }
    int i2 = 0; double b2 = dh[32] - Gl[i0 * 48 + 32] - Gl[(16 + i1) * 48 + 32];
#pragma unroll
    for (int c = 1; c < 16; c++) {
      double s = dh[32 + c] - Gl[i0 * 48 + 32 + c] - Gl[(16 + i1) * 48 + 32 + c];
      if (s > b2) { b2 = s; i2 = c; }
    }
    double r1s = hh[n] - 2.0 * b0 + Gl[i0 * 48 + i0];
    double r2s = r1s - 2.0 * b1 + Gl[(16 + i1) * 48 + 16 + i1];
    double r3s = r2s - 2.0 * b2 + Gl[(32 + i2) * 48 + 32 + i2];
    csum = r1s + r2s + r3s;
    const long IDS_BASE = (long)NGRAPH * DIM * NLAY + (long)N_NODES * DIM * NLAY + 1;
    long base = IDS_BASE + n * (NLAY * NRES) + l * NRES;
    stout(out, base + 0, (double)i0, isbf);
    stout(out, base + 1, (double)i1, isbf);
    stout(out, base + 2, (double)i2, isbf);
  }
  for (int o = 32; o; o >>= 1) csum += __shfl_xor(csum, o);
  if ((tid & 63) == 0 && csum != 0.0) atomAddD(commit, csum);
}

// ---------- final: xpool + commit -> out ----------
__global__ __launch_bounds__(256) void k_out(const double* __restrict__ xpool, const double* __restrict__ commit,
                                             void* __restrict__ out, const int* __restrict__ flag) {
  int isbf = flag[0];
  long i = (long)blockIdx.x * 256 + threadIdx.x;
  const long NP = (long)NGRAPH * DIM * NLAY;
  if (i < NP) {
    stout(out, i, xpool[i], isbf);
  } else if (i == NP) {
    double c = commit[0] * (0.25 / ((double)N_NODES * (double)DIM));
    stout(out, NP + (long)N_NODES * DIM * NLAY, c, isbf);
  }
}

extern "C" void kernel_launch(void* const* d_in, const int* in_sizes, int n_in,
                              void* d_out, int out_size, void* d_ws, size_t ws_size,
                              hipStream_t stream) {
  const void* x = d_in[0];
  const int* ei = (const int*)d_in[1];
  const int* batch = (const int*)d_in[2];
  const void* W1 = d_in[3];
  const void* b1 = d_in[4];
  const void* W2 = d_in[5];
  const void* b2 = d_in[6];
  const void* gamma = d_in[7];
  const void* beta = d_in[8];
  const void* cb = d_in[9];

  double* w = (double*)d_ws;
  double* A = w;                        // 12,800,000
  double* B = A + 12800000;             // 12,800,000
  double* cbn = B + 12800000;           // 18,432
  double* G = cbn + 18432;              // 6,912
  double* stats = G + 6912;             // 256
  double* ss = stats + 256;             // 256
  double* hh = ss + 256;                // 100,000
  double* dH = hh + N_NODES;            // 4,800,000
  double* xpool = dH + (long)N_NODES * 48;             // 196,608
  double* commit = xpool + (long)NGRAPH * DIM * NLAY;  // 1
  double* W1d = commit + 1;             // 49,152
  double* W2d = W1d + 49152;            // 49,152
  double* b1d = W2d + 49152;            // 384
  double* b2d = b1d + 384;              // 384
  int* flag = (int*)(b2d + 384);        // 1 int

  k_detect<<<1, 256, 0, stream>>>((const unsigned int*)x, flag);
  // zero accumulators (xpool + commit contiguous)
  hipMemsetAsync(xpool, 0, ((long)NGRAPH * DIM * NLAY + 1) * sizeof(double), stream);
  k_convert<<<50000, 256, 0, stream>>>(x, A, (long)N_NODES * DIM, flag);
  k_convert<<<192, 256, 0, stream>>>(W1, W1d, 49152, flag);
  k_convert<<<192, 256, 0, stream>>>(W2, W2d, 49152, flag);
  k_convert<<<2, 256, 0, stream>>>(b1, b1d, 384, flag);
  k_convert<<<2, 256, 0, stream>>>(b2, b2d, 384, flag);
  k_cbn<<<NLAY * NRES * NCODE, 64, 0, stream>>>(cb, cbn, flag);
  k_gram<<<NLAY * 48 * 48, 64, 0, stream>>>(cbn, G);

  double* P = A; double* Q = B;
  for (int l = 0; l < NLAY; l++) {
    k_copy<<<25000, 256, 0, stream>>>(P, Q);
    k_scatter<<<400000, 256, 0, stream>>>(ei, P, Q);
    k_gemm_relu<<<3125, 256, 0, stream>>>(Q, W1d + l * DIM * DIM, b1d + l * DIM, P);
    k_gemm_relu<<<3125, 256, 0, stream>>>(P, W2d + l * DIM * DIM, b2d + l * DIM, Q);
    hipMemsetAsync(stats, 0, 256 * sizeof(double), stream);
    k_bn_stats<<<1024, 256, 0, stream>>>(Q, stats);
    k_bn_prep<<<1, 128, 0, stream>>>(stats, gamma, beta, ss, l, flag);
    k_normalize<<<50000, 256, 0, stream>>>(Q, ss, batch, d_out, xpool, hh, l, flag);
    k_dotH<<<1563, 256, 0, stream>>>(Q, cbn + (long)l * 48 * DIM, dH);
    k_vq<<<391, 256, 0, stream>>>(dH, hh, G + l * 48 * 48, d_out, commit, l, flag);
    double* t = P; P = Q; Q = t;
  }
  k_out<<<769, 256, 0, stream>>>(xpool, commit, d_out, flag);
}

// Round 4
// 2918.443 us; speedup vs baseline: 3.0004x; 3.0004x over previous
//
#include <hip/hip_runtime.h>
#include <hip/hip_bf16.h>

#define N_NODES 100000
#define N_EDGES 1600000
#define DIM 128
#define NLAY 3
#define NRES 3
#define NCODE 16
#define NGRAPH 512

using bf16 = __hip_bfloat16;

__device__ inline void atomAddD(double* p, double v) { unsafeAtomicAdd(p, v); }

// flag==1: external float-typed arrays are bf16; flag==0: they are fp32.
__device__ inline double ldx(const void* p, long i, int isbf) {
  if (isbf) return (double)__bfloat162float(((const bf16*)p)[i]);
  return (double)((const float*)p)[i];
}
__device__ inline void stout(void* p, long i, double v, int isbf) {
  if (isbf) ((bf16*)p)[i] = __float2bfloat16((float)v);
  else ((float*)p)[i] = (float)v;
}

// ---------- dtype detection: bf16 vs fp32 bit-pattern statistics ----------
__global__ void k_detect(const unsigned int* __restrict__ x, int* __restrict__ flag) {
  int tid = threadIdx.x;  // 256
  int cnt = 0;
  for (int j = tid; j < 1024; j += 256) {
    unsigned int u = x[j];
    int e = (u >> 7) & 0xFF;  // exponent field of the LOW u16 viewed as bf16
    cnt += (e >= 100 && e <= 135) ? 1 : 0;
  }
  __shared__ int sh[256];
  sh[tid] = cnt; __syncthreads();
  for (int s = 128; s; s >>= 1) { if (tid < s) sh[tid] += sh[tid + s]; __syncthreads(); }
  if (tid == 0) flag[0] = (sh[0] > 512) ? 1 : 0;
}

// ---------- external -> fp64 convert ----------
__global__ __launch_bounds__(256) void k_convert(const void* __restrict__ x, double* __restrict__ A,
                                                 long n, const int* __restrict__ flag) {
  int isbf = flag[0];
  long i = (long)blockIdx.x * 256 + threadIdx.x;
  if (i < n) A[i] = ldx(x, i, isbf);
}

// ---------- CSR build: histogram ----------
__global__ __launch_bounds__(256) void k_hist(const int* __restrict__ ei, int* __restrict__ deg) {
  int e = blockIdx.x * 256 + threadIdx.x;
  if (e < N_EDGES) atomicAdd(&deg[ei[N_EDGES + e]], 1);
}

// ---------- CSR build: exclusive scan (1 block) ----------
__global__ void k_scan(const int* __restrict__ deg, int* __restrict__ ofs, int* __restrict__ cursor) {
  __shared__ int sums[256];
  int t = threadIdx.x;
  const int CH = (N_NODES + 255) / 256;
  int lo = t * CH; int hi = lo + CH; if (hi > N_NODES) hi = N_NODES;
  int s = 0;
  for (int i = lo; i < hi; i++) s += deg[i];
  sums[t] = s; __syncthreads();
  if (t == 0) { int run = 0; for (int i = 0; i < 256; i++) { int v = sums[i]; sums[i] = run; run += v; } }
  __syncthreads();
  int run = sums[t];
  for (int i = lo; i < hi; i++) { ofs[i] = run; cursor[i] = run; run += deg[i]; }
  if (t == 255) ofs[N_NODES] = N_EDGES;
}

// ---------- CSR build: fill ----------
__global__ __launch_bounds__(256) void k_fill(const int* __restrict__ ei, int* __restrict__ cursor,
                                              int* __restrict__ csr) {
  int e = blockIdx.x * 256 + threadIdx.x;
  if (e < N_EDGES) {
    int d = ei[N_EDGES + e];
    int p = atomicAdd(&cursor[d], 1);
    csr[p] = ei[e];
  }
}

// ---------- gather: Q[n] = h[n] + sum_{j in in(n)} h[src_j]  (one wave per node) ----------
__global__ __launch_bounds__(256) void k_gather(const double* __restrict__ h,
                                                const int* __restrict__ ofs,
                                                const int* __restrict__ csr,
                                                double* __restrict__ outQ) {
  int node = blockIdx.x * 4 + (threadIdx.x >> 6);
  int lane = threadIdx.x & 63;
  int beg = ofs[node], end = ofs[node + 1];
  double2 acc = *(const double2*)&h[(long)node * DIM + lane * 2];
  int j = beg;
  for (; j + 1 < end; j += 2) {
    int s0 = csr[j], s1 = csr[j + 1];
    double2 v0 = *(const double2*)&h[(long)s0 * DIM + lane * 2];
    double2 v1 = *(const double2*)&h[(long)s1 * DIM + lane * 2];
    acc.x += v0.x + v1.x;
    acc.y += v0.y + v1.y;
  }
  if (j < end) {
    int s0 = csr[j];
    double2 v0 = *(const double2*)&h[(long)s0 * DIM + lane * 2];
    acc.x += v0.x;
    acc.y += v0.y;
  }
  *(double2*)&outQ[(long)node * DIM + lane * 2] = acc;
}

// ---------- normalize codebooks (fp64) ----------
__global__ void k_cbn(const void* __restrict__ cb, double* __restrict__ cbn, const int* __restrict__ flag) {
  int isbf = flag[0];
  int b = blockIdx.x, d = threadIdx.x;  // 144 blocks x 64 threads
  double v0 = ldx(cb, (long)b * DIM + d, isbf);
  double v1 = ldx(cb, (long)b * DIM + d + 64, isbf);
  double ss = v0 * v0 + v1 * v1;
  for (int o = 32; o; o >>= 1) ss += __shfl_xor(ss, o);
  double inv = 1.0 / sqrt(ss + 1e-12);
  cbn[b * DIM + d] = v0 * inv;
  cbn[b * DIM + d + 64] = v1 * inv;
}

// ---------- Gram matrices per layer ----------
__global__ void k_gram(const double* __restrict__ cbn, double* __restrict__ G) {
  int b = blockIdx.x, t = threadIdx.x;  // 3*48*48 blocks x 64
  int l = b / (48 * 48); int rem = b % (48 * 48); int a = rem / 48, c = rem % 48;
  const double* ra = cbn + (long)(l * 48 + a) * DIM;
  const double* rc = cbn + (long)(l * 48 + c) * DIM;
  double s = ra[t] * rc[t] + ra[t + 64] * rc[t + 64];
  for (int o = 32; o; o >>= 1) s += __shfl_xor(s, o);
  if (t == 0) G[b] = s;
}

// ---------- fp64 GEMM + bias + relu ----------
__global__ __launch_bounds__(256) void k_gemm_relu(const double* __restrict__ in,
                                                   const double* __restrict__ W,
                                                   const double* __restrict__ bias,
                                                   double* __restrict__ out) {
  __shared__ double ul[32 * DIM];
  int tid = threadIdx.x;
  long base = (long)blockIdx.x * 32;
  for (int j = tid; j < 32 * DIM; j += 256) ul[j] = in[base * DIM + j];
  __syncthreads();
  int c = 2 * (tid & 63);
  int tr = tid >> 6;
  double acc[8][2] = {};
  for (int k = 0; k < DIM; k += 2) {
    double2 wa = *(const double2*)&W[k * DIM + c];
    double2 wb = *(const double2*)&W[(k + 1) * DIM + c];
#pragma unroll
    for (int rg = 0; rg < 8; rg++) {
      double2 u = *(const double2*)&ul[(rg * 4 + tr) * DIM + k];
      acc[rg][0] += u.x * wa.x + u.y * wb.x;
      acc[rg][1] += u.x * wa.y + u.y * wb.y;
    }
  }
  double2 bv = *(const double2*)&bias[c];
#pragma unroll
  for (int rg = 0; rg < 8; rg++) {
    double v0 = acc[rg][0] + bv.x;
    double v1 = acc[rg][1] + bv.y;
    v0 = v0 > 0.0 ? v0 : 0.0;
    v1 = v1 > 0.0 ? v1 : 0.0;
    *(double2*)&out[(base + rg * 4 + tr) * DIM + c] = make_double2(v0, v1);
  }
}

// ---------- BN stats ----------
__global__ __launch_bounds__(256) void k_bn_stats(const double* __restrict__ h, double* __restrict__ stats) {
  int tid = threadIdx.x; int col = tid & 127; int half = tid >> 7;
  double s = 0.0, s2 = 0.0;
  for (long r = blockIdx.x * 2 + half; r < N_NODES; r += 2048) {
    double v = h[r * DIM + col];
    s += v; s2 += v * v;
  }
  __shared__ double ls[256], ls2[256];
  ls[tid] = s; ls2[tid] = s2;
  __syncthreads();
  if (tid < 128) {
    atomAddD(&stats[col], ls[tid] + ls[tid + 128]);
    atomAddD(&stats[DIM + col], ls2[tid] + ls2[tid + 128]);
  }
}

// ---------- BN prep ----------
__global__ void k_bn_prep(const double* __restrict__ stats, const void* __restrict__ gamma,
                          const void* __restrict__ beta, double* __restrict__ ss,
                          int l, const int* __restrict__ flag) {
  int isbf = flag[0];
  int d = threadIdx.x;  // 128
  double mean = stats[d] / (double)N_NODES;
  double var = stats[DIM + d] / (double)N_NODES - mean * mean;
  double sc = ldx(gamma, (long)l * DIM + d, isbf) / sqrt(var + 1e-5);
  ss[d] = sc;
  ss[DIM + d] = ldx(beta, (long)l * DIM + d, isbf) - mean * sc;
}

// ---------- normalize in place + xs out + xpool + ||h||^2 ----------
__global__ __launch_bounds__(256) void k_normalize(double* __restrict__ h, const double* __restrict__ ss,
                                                   const int* __restrict__ batch, void* __restrict__ out,
                                                   double* __restrict__ xpool, double* __restrict__ hh,
                                                   int l, const int* __restrict__ flag) {
  int isbf = flag[0];
  int tid = threadIdx.x;
  int n = blockIdx.x * 2 + (tid >> 7);
  int d = tid & 127;
  double v = h[(long)n * DIM + d] * ss[d] + ss[DIM + d];
  h[(long)n * DIM + d] = v;
  const long XS_BASE = (long)NGRAPH * DIM * NLAY;
  stout(out, XS_BASE + (long)n * (DIM * NLAY) + l * DIM + d, v, isbf);
  int g = batch[n];
  atomAddD(&xpool[(long)g * (DIM * NLAY) + l * DIM + d], v);
  double s2 = v * v;
  for (int o = 32; o; o >>= 1) s2 += __shfl_xor(s2, o);
  __shared__ double wp[4];
  if ((tid & 63) == 0) wp[tid >> 6] = s2;
  __syncthreads();
  if (tid == 0) hh[n] = wp[0] + wp[1];
  else if (tid == 128) hh[n] = wp[2] + wp[3];
}

// ---------- dotH = h_norm @ cbn^T (48 cols), fp64 ----------
__global__ __launch_bounds__(256) void k_dotH(const double* __restrict__ hn,
                                              const double* __restrict__ cbnL,
                                              double* __restrict__ dH) {
  __shared__ double cl[48 * 134];
  int tid = threadIdx.x;
  for (int j = tid; j < 48 * DIM; j += 256) { int c = j >> 7, k = j & 127; cl[c * 134 + k] = cbnL[j]; }
  __syncthreads();
  int ct = tid & 7; int c0 = ct * 6; int rt = tid >> 3;
  long r0 = (long)blockIdx.x * 64 + rt; long r1 = r0 + 32;
  long r0c = r0 < N_NODES ? r0 : (N_NODES - 1);
  long r1c = r1 < N_NODES ? r1 : (N_NODES - 1);
  double acc0[6] = {}, acc1[6] = {};
  for (int k = 0; k < DIM; k += 2) {
    double2 h0 = *(const double2*)&hn[r0c * DIM + k];
    double2 h1 = *(const double2*)&hn[r1c * DIM + k];
#pragma unroll
    for (int j = 0; j < 6; j++) {
      double2 cv = *(const double2*)&cl[(c0 + j) * 134 + k];
      acc0[j] += h0.x * cv.x + h0.y * cv.y;
      acc1[j] += h1.x * cv.x + h1.y * cv.y;
    }
  }
  if (r0 < N_NODES) {
#pragma unroll
    for (int j = 0; j < 6; j++) dH[r0 * 48 + c0 + j] = acc0[j];
  }
  if (r1 < N_NODES) {
#pragma unroll
    for (int j = 0; j < 6; j++) dH[r1 * 48 + c0 + j] = acc1[j];
  }
}

// ---------- VQ select via dotH & Gram; ids + commit ----------
__global__ __launch_bounds__(256) void k_vq(const double* __restrict__ dH, const double* __restrict__ hh,
                                            const double* __restrict__ G, void* __restrict__ out,
                                            double* __restrict__ commit, int l, const int* __restrict__ flag) {
  int isbf = flag[0];
  __shared__ double Gl[48 * 48];
  int tid = threadIdx.x;
  for (int j = tid; j < 48 * 48; j += 256) Gl[j] = G[j];
  __syncthreads();
  long n = (long)blockIdx.x * 256 + tid;
  double csum = 0.0;
  if (n < N_NODES) {
    double dh[48];
#pragma unroll
    for (int c = 0; c < 48; c++) dh[c] = dH[n * 48 + c];
    int i0 = 0; double b0 = dh[0];
#pragma unroll
    for (int c = 1; c < 16; c++) { if (dh[c] > b0) { b0 = dh[c]; i0 = c; } }
    int i1 = 0; double b1 = dh[16] - Gl[i0 * 48 + 16];
#pragma unroll
    for (int c = 1; c < 16; c++) {
      double s = dh[16 + c] - Gl[i0 * 48 + 16 + c];
      if (s > b1) { b1 = s; i1 = c; }
    }
    int i2 = 0; double b2 = dh[32] - Gl[i0 * 48 + 32] - Gl[(16 + i1) * 48 + 32];
#pragma unroll
    for (int c = 1; c < 16; c++) {
      double s = dh[32 + c] - Gl[i0 * 48 + 32 + c] - Gl[(16 + i1) * 48 + 32 + c];
      if (s > b2) { b2 = s; i2 = c; }
    }
    double r1s = hh[n] - 2.0 * b0 + Gl[i0 * 48 + i0];
    double r2s = r1s - 2.0 * b1 + Gl[(16 + i1) * 48 + 16 + i1];
    double r3s = r2s - 2.0 * b2 + Gl[(32 + i2) * 48 + 32 + i2];
    csum = r1s + r2s + r3s;
    const long IDS_BASE = (long)NGRAPH * DIM * NLAY + (long)N_NODES * DIM * NLAY + 1;
    long base = IDS_BASE + n * (NLAY * NRES) + l * NRES;
    stout(out, base + 0, (double)i0, isbf);
    stout(out, base + 1, (double)i1, isbf);
    stout(out, base + 2, (double)i2, isbf);
  }
  for (int o = 32; o; o >>= 1) csum += __shfl_xor(csum, o);
  if ((tid & 63) == 0 && csum != 0.0) atomAddD(commit, csum);
}

// ---------- final: xpool + commit -> out ----------
__global__ __launch_bounds__(256) void k_out(const double* __restrict__ xpool, const double* __restrict__ commit,
                                             void* __restrict__ out, const int* __restrict__ flag) {
  int isbf = flag[0];
  long i = (long)blockIdx.x * 256 + threadIdx.x;
  const long NP = (long)NGRAPH * DIM * NLAY;
  if (i < NP) {
    stout(out, i, xpool[i], isbf);
  } else if (i == NP) {
    double c = commit[0] * (0.25 / ((double)N_NODES * (double)DIM));
    stout(out, NP + (long)N_NODES * DIM * NLAY, c, isbf);
  }
}

extern "C" void kernel_launch(void* const* d_in, const int* in_sizes, int n_in,
                              void* d_out, int out_size, void* d_ws, size_t ws_size,
                              hipStream_t stream) {
  const void* x = d_in[0];
  const int* ei = (const int*)d_in[1];
  const int* batch = (const int*)d_in[2];
  const void* W1 = d_in[3];
  const void* b1 = d_in[4];
  const void* W2 = d_in[5];
  const void* b2 = d_in[6];
  const void* gamma = d_in[7];
  const void* beta = d_in[8];
  const void* cb = d_in[9];

  double* w = (double*)d_ws;
  double* A = w;                        // 12,800,000
  double* B = A + 12800000;             // 12,800,000
  double* cbn = B + 12800000;           // 18,432
  double* G = cbn + 18432;              // 6,912
  double* stats = G + 6912;             // 256
  double* ss = stats + 256;             // 256
  double* hh = ss + 256;                // 100,000
  double* dH = hh + N_NODES;            // 4,800,000
  double* xpool = dH + (long)N_NODES * 48;             // 196,608
  double* commit = xpool + (long)NGRAPH * DIM * NLAY;  // 1
  double* W1d = commit + 1;             // 49,152
  double* W2d = W1d + 49152;            // 49,152
  double* b1d = W2d + 49152;            // 384
  double* b2d = b1d + 384;              // 384
  int* ibuf = (int*)(b2d + 384);
  int* flag = ibuf;                     // 1
  int* deg = ibuf + 64;                 // N_NODES
  int* ofs = deg + N_NODES;             // N_NODES + 1
  int* cursor = ofs + N_NODES + 1;      // N_NODES
  int* csr = cursor + N_NODES;          // N_EDGES

  k_detect<<<1, 256, 0, stream>>>((const unsigned int*)x, flag);
  // zero accumulators (xpool + commit contiguous)
  hipMemsetAsync(xpool, 0, ((long)NGRAPH * DIM * NLAY + 1) * sizeof(double), stream);
  hipMemsetAsync(deg, 0, N_NODES * sizeof(int), stream);
  k_convert<<<50000, 256, 0, stream>>>(x, A, (long)N_NODES * DIM, flag);
  k_convert<<<192, 256, 0, stream>>>(W1, W1d, 49152, flag);
  k_convert<<<192, 256, 0, stream>>>(W2, W2d, 49152, flag);
  k_convert<<<2, 256, 0, stream>>>(b1, b1d, 384, flag);
  k_convert<<<2, 256, 0, stream>>>(b2, b2d, 384, flag);
  k_cbn<<<NLAY * NRES * NCODE, 64, 0, stream>>>(cb, cbn, flag);
  k_gram<<<NLAY * 48 * 48, 64, 0, stream>>>(cbn, G);
  // CSR build (once; reused all 3 layers)
  k_hist<<<(N_EDGES + 255) / 256, 256, 0, stream>>>(ei, deg);
  k_scan<<<1, 256, 0, stream>>>(deg, ofs, cursor);
  k_fill<<<(N_EDGES + 255) / 256, 256, 0, stream>>>(ei, cursor, csr);

  double* P = A; double* Q = B;
  for (int l = 0; l < NLAY; l++) {
    k_gather<<<N_NODES / 4, 256, 0, stream>>>(P, ofs, csr, Q);
    k_gemm_relu<<<3125, 256, 0, stream>>>(Q, W1d + l * DIM * DIM, b1d + l * DIM, P);
    k_gemm_relu<<<3125, 256, 0, stream>>>(P, W2d + l * DIM * DIM, b2d + l * DIM, Q);
    hipMemsetAsync(stats, 0, 256 * sizeof(double), stream);
    k_bn_stats<<<1024, 256, 0, stream>>>(Q, stats);
    k_bn_prep<<<1, 128, 0, stream>>>(stats, gamma, beta, ss, l, flag);
    k_normalize<<<50000, 256, 0, stream>>>(Q, ss, batch, d_out, xpool, hh, l, flag);
    k_dotH<<<1563, 256, 0, stream>>>(Q, cbn + (long)l * 48 * DIM, dH);
    k_vq<<<391, 256, 0, stream>>>(dH, hh, G + l * 48 * 48, d_out, commit, l, flag);
    double* t = P; P = Q; Q = t;
  }
  k_out<<<769, 256, 0, stream>>>(xpool, commit, d_out, flag);
}